// Round 1
// 187.910 us; speedup vs baseline: 1.0513x; 1.0513x over previous
//
#include <hip/hip_runtime.h>

#define KK 8
#define NA 8
#define NB 64
#define NH 256
#define NW 256
#define HP (NH - KK + 1)   // 249
#define WP (NW - KK + 1)   // 249

typedef __attribute__((ext_vector_type(4))) float f32x4;

// Stage 1: sm[a][y][x] = exp( (1/64) * sum_b x[a][b][y][x] )
// One float4 per thread, full 64-channel reduction. 512 blocks = 2 waves/SIMD.
// x is read exactly once globally -> non-temporal loads (nt flag) so the
// 134 MB stream doesn't thrash L1/L2 (keeps sm/cnt lines resident for stage 2).
// unroll 32 keeps 32 dwordx4 loads in flight per lane (512 B/lane, far above
// the ~9 KB/CU needed to cover 900-cyc HBM latency at 24.6 GB/s/CU).
__global__ __launch_bounds__(256) void k_mean_exp(const float* __restrict__ x,
                                                  float* __restrict__ sm) {
    int tid = blockIdx.x * 256 + threadIdx.x;   // 0 .. A*H*W/4-1
    int a = tid >> 14;                          // H*W/4 = 16384 float4 per image
    int p4 = tid & 16383;
    const f32x4* xp = (const f32x4*)(x + (size_t)a * NB * (NH * NW)) + p4;
    f32x4 acc = {0.f, 0.f, 0.f, 0.f};
    #pragma unroll 32
    for (int b = 0; b < NB; ++b) {
        f32x4 v = __builtin_nontemporal_load(xp + (size_t)b * (NH * NW / 4));
        acc += v;
    }
    const float s = 1.0f / NB;
    f32x4 r;
    r.x = __expf(acc.x * s);
    r.y = __expf(acc.y * s);
    r.z = __expf(acc.z * s);
    r.w = __expf(acc.w * s);
    ((f32x4*)sm)[tid] = r;
}

// Stage 2 (fused): per 32x32 output tile, stage the 46x46 sm tile (7-halo)
// into LDS, then separable box sums: hrs (horiz 8-sum), t = c/sc with OOB
// zeroed, vs (vert 8-sum of t), out = sm_center * horiz 8-sum of vs.
// 512 blocks x 16 waves = 8192 waves = exactly full occupancy (256 CU x 32).
__global__ __launch_bounds__(1024) void k_fused(const float* __restrict__ sm,
                                                const float* __restrict__ cnt,
                                                float* __restrict__ out) {
    __shared__ float s_sm[46 * 48];
    __shared__ float hrs[46 * 40];
    __shared__ float t_s[39 * 40];
    __shared__ float vs[32 * 40];
    const int tx = threadIdx.x, ty = threadIdx.y;
    const int tid = ty * 32 + tx;
    const int a = blockIdx.z;
    const int y0 = blockIdx.y * 32, x0 = blockIdx.x * 32;
    const float* sa = sm + (size_t)a * (NH * NW);

    // sm tile: 46x46, coords clamped (clamped entries only feed invalid t)
    for (int idx = tid; idx < 46 * 46; idx += 1024) {
        int r = idx / 46, cc = idx - r * 46;
        int rg = y0 - 7 + r;  rg = rg < 0 ? 0 : (rg > NH - 1 ? NH - 1 : rg);
        int cg = x0 - 7 + cc; cg = cg < 0 ? 0 : (cg > NW - 1 ? NW - 1 : cg);
        s_sm[r * 48 + cc] = sa[rg * NW + cg];
    }
    __syncthreads();

    // horizontal 8-sums: hrs[r][c] = sum_j sm[r][c+j], 46x39
    for (int idx = tid; idx < 46 * 39; idx += 1024) {
        int r = idx / 39, cc = idx - r * 39;
        const float* row = &s_sm[r * 48 + cc];
        hrs[r * 40 + cc] = row[0] + row[1] + row[2] + row[3] +
                           row[4] + row[5] + row[6] + row[7];
    }
    __syncthreads();

    // t = c / sc (vertical 8-sum of hrs), zero when (ph,pw) outside valid range
    const float* ca = cnt + (size_t)a * (HP * WP);
    for (int idx = tid; idx < 39 * 39; idx += 1024) {
        int r = idx / 39, cc = idx - r * 39;
        float sc = 0.f;
        #pragma unroll
        for (int i = 0; i < 8; ++i) sc += hrs[(r + i) * 40 + cc];
        int ph = y0 - 7 + r, pw = x0 - 7 + cc;
        float tv = 0.f;
        if ((unsigned)ph < (unsigned)HP && (unsigned)pw < (unsigned)WP)
            tv = ca[ph * WP + pw] / sc;
        t_s[r * 40 + cc] = tv;
    }
    __syncthreads();

    // vertical 8-sums of t: vs[r][c] = sum_i t[r+i][c], 32x39
    for (int idx = tid; idx < 32 * 39; idx += 1024) {
        int r = idx / 39, cc = idx - r * 39;
        float s = 0.f;
        #pragma unroll
        for (int i = 0; i < 8; ++i) s += t_s[(r + i) * 40 + cc];
        vs[r * 40 + cc] = s;
    }
    __syncthreads();

    // out = sm_center * horizontal 8-sum of vs; out is never re-read -> nt store
    float s = 0.f;
    #pragma unroll
    for (int j = 0; j < 8; ++j) s += vs[ty * 40 + tx + j];
    float ov = s_sm[(ty + 7) * 48 + tx + 7] * s;
    __builtin_nontemporal_store(ov, &out[((size_t)a * NH + (y0 + ty)) * NW + (x0 + tx)]);
}

extern "C" void kernel_launch(void* const* d_in, const int* in_sizes, int n_in,
                              void* d_out, int out_size, void* d_ws, size_t ws_size,
                              hipStream_t stream) {
    const float* x = (const float*)d_in[0];   // (8,64,256,256) f32
    const float* c = (const float*)d_in[1];   // (8,1,249,249)  f32
    float* out = (float*)d_out;               // (8,1,256,256)  f32
    float* sm  = (float*)d_ws;                // 2 MB

    k_mean_exp<<<(NA * NH * NW / 4) / 256, 256, 0, stream>>>(x, sm);
    dim3 grid(NW / 32, NH / 32, NA);          // (8,8,8)
    dim3 block(32, 32);
    k_fused<<<grid, block, 0, stream>>>(sm, c, out);
}